// Round 4
// baseline (371.108 us; speedup 1.0000x reference)
//
#include <hip/hip_runtime.h>
#include <hip/hip_bf16.h>
#include <hip/hip_fp16.h>
#include <math.h>

// Problem constants
#define TOKENS   8192
#define DIM      4096
#define NEXP     256
#define TOPK     8
#define CAND     12

// GEMM tiling
#define MT4      64                // tokens per block
#define BK3      64                // k per staged chunk
#define KG       (DIM / 32)        // 128 k-fragment-groups in W

// rescore K-split
#define KSL      8                 // k slices (= XCD count)
#define KSW      (DIM / KSL)       // 512 floats per slice

typedef _Float16 f16x8 __attribute__((ext_vector_type(8)));
typedef float    f32x4 __attribute__((ext_vector_type(4)));

typedef const __attribute__((address_space(1))) unsigned int* gas_ptr;
typedef       __attribute__((address_space(3))) unsigned int* las_ptr;

// ---------------------------------------------------------------------------
// Kernel 0: W fp32 -> fp16 in MFMA-B-fragment-swizzled order.
// 1 KB tiles, tile = ng*KG + kg covers experts [ng*16,+16) x k [kg*32,+32);
// chunk c = q*16+r holds B[n=ng*16+r][k=kg*32+q*8..+8] = lane c's B-fragment.
// ---------------------------------------------------------------------------
__global__ __launch_bounds__(256)
void convert_w(const float* __restrict__ w, _Float16* __restrict__ whs) {
    const int g = blockIdx.x * 256 + threadIdx.x;   // chunk id, 131072 total
    const int tile = g >> 6, c = g & 63;
    const int q = c >> 4, r = c & 15;
    const int ng = tile / KG, kg = tile % KG;
    const int n = ng * 16 + r, k = kg * 32 + q * 8;
    const float4 a = *(const float4*)(w + (size_t)n * DIM + k);
    const float4 b = *(const float4*)(w + (size_t)n * DIM + k + 4);
    f16x8 h;
    h[0] = (_Float16)a.x; h[1] = (_Float16)a.y;
    h[2] = (_Float16)a.z; h[3] = (_Float16)a.w;
    h[4] = (_Float16)b.x; h[5] = (_Float16)b.y;
    h[6] = (_Float16)b.z; h[7] = (_Float16)b.w;
    *(f16x8*)(whs + (size_t)g * 8) = h;
}

// ---------------------------------------------------------------------------
// Kernel 1: partial logits via fp16 MFMA, K-split over blockIdx.y.
// Block: 64 tokens x 256 experts, 256 thr = 4 waves, wave-tile 64x64
// (16 MFMA / 8KB LDS-read). LDS 40 KB -> 3 blocks/CU; grid 128*S blocks.
// B staged via global_load_lds(16B) from pre-swizzled whs; A cvt'd on the fly.
// x loads are NONTEMPORAL (read-once stream) so whs stays L2-resident.
// ---------------------------------------------------------------------------
__global__ __launch_bounds__(256, 3)
void gemm_v4(const float* __restrict__ x, const _Float16* __restrict__ whs,
             float* __restrict__ logits, int kspan) {
    __shared__ _Float16 As[8 * 512];    //  8 tiles x 1 KB = 8 KB
    __shared__ _Float16 Bs[32 * 512];   // 32 tiles x 1 KB = 32 KB

    const int t = threadIdx.x, w = t >> 6, lane = t & 63;
    const int m0 = blockIdx.x * MT4;
    const int kb = blockIdx.y * kspan;
    float* lp    = logits + (size_t)blockIdx.y * TOKENS * NEXP;

    // A staging: thread t -> row am (0..63), k-chunks ack, ack+1 (8 halves ea)
    const int am  = t >> 2;
    const int ack = (t & 3) * 2;
    const int amg = am >> 4, amr = am & 15;
    const int aoff0 = ((amg * 2 + (ack >> 2)) * 64 + (ack & 3) * 16 + amr) * 8;
    const int ack1  = ack + 1;
    const int aoff1 = ((amg * 2 + (ack1 >> 2)) * 64 + (ack1 & 3) * 16 + amr) * 8;

    f32x4 acc[4][4];
    #pragma unroll
    for (int i = 0; i < 4; ++i)
        #pragma unroll
        for (int j = 0; j < 4; ++j) acc[i][j] = (f32x4){0.f, 0.f, 0.f, 0.f};

    const float* xrow = x + (size_t)(m0 + am) * DIM + ack * 8;
    f32x4 xr0 = __builtin_nontemporal_load((const f32x4*)(xrow + kb));
    f32x4 xr1 = __builtin_nontemporal_load((const f32x4*)(xrow + kb + 4));
    f32x4 xr2 = __builtin_nontemporal_load((const f32x4*)(xrow + kb + 8));
    f32x4 xr3 = __builtin_nontemporal_load((const f32x4*)(xrow + kb + 12));

    for (int k0 = kb; k0 < kb + kspan; k0 += BK3) {
        // B DMA: wave w stages tiles ti = w*8 .. w*8+7
        #pragma unroll
        for (int c = 0; c < 8; ++c) {
            const int ti  = w * 8 + c;
            const int ng  = ti >> 1, kgl = ti & 1;
            const _Float16* gp = whs + ((size_t)(ng * KG + (k0 >> 5) + kgl)) * 512
                                     + lane * 8;
            __builtin_amdgcn_global_load_lds((gas_ptr)gp, (las_ptr)&Bs[ti * 512],
                                             16, 0, 0);
        }
        // A cvt + frag-order ds_write
        {
            f16x8 h0, h1;
            h0[0] = (_Float16)xr0.x; h0[1] = (_Float16)xr0.y;
            h0[2] = (_Float16)xr0.z; h0[3] = (_Float16)xr0.w;
            h0[4] = (_Float16)xr1.x; h0[5] = (_Float16)xr1.y;
            h0[6] = (_Float16)xr1.z; h0[7] = (_Float16)xr1.w;
            h1[0] = (_Float16)xr2.x; h1[1] = (_Float16)xr2.y;
            h1[2] = (_Float16)xr2.z; h1[3] = (_Float16)xr2.w;
            h1[4] = (_Float16)xr3.x; h1[5] = (_Float16)xr3.y;
            h1[6] = (_Float16)xr3.z; h1[7] = (_Float16)xr3.w;
            *(f16x8*)&As[aoff0] = h0;
            *(f16x8*)&As[aoff1] = h1;
        }
        __syncthreads();

        if (k0 + BK3 < kb + kspan) {
            xr0 = __builtin_nontemporal_load((const f32x4*)(xrow + k0 + BK3));
            xr1 = __builtin_nontemporal_load((const f32x4*)(xrow + k0 + BK3 + 4));
            xr2 = __builtin_nontemporal_load((const f32x4*)(xrow + k0 + BK3 + 8));
            xr3 = __builtin_nontemporal_load((const f32x4*)(xrow + k0 + BK3 + 12));
        }

        #pragma unroll
        for (int kk = 0; kk < 2; ++kk) {
            f16x8 af[4], bf[4];
            #pragma unroll
            for (int mt = 0; mt < 4; ++mt)
                af[mt] = *(const f16x8*)&As[((mt * 2 + kk) * 64 + lane) * 8];
            #pragma unroll
            for (int nt = 0; nt < 4; ++nt)
                bf[nt] = *(const f16x8*)&Bs[(((w * 4 + nt) * 2 + kk) * 64 + lane) * 8];
            #pragma unroll
            for (int mt = 0; mt < 4; ++mt)
                #pragma unroll
                for (int nt = 0; nt < 4; ++nt)
                    acc[mt][nt] = __builtin_amdgcn_mfma_f32_16x16x32_f16(
                        af[mt], bf[nt], acc[mt][nt], 0, 0, 0);
        }
        __syncthreads();
    }

    // epilogue: C/D layout col=lane&15, row=(lane>>4)*4+reg
    #pragma unroll
    for (int mt = 0; mt < 4; ++mt) {
        #pragma unroll
        for (int nt = 0; nt < 4; ++nt) {
            #pragma unroll
            for (int r = 0; r < 4; ++r) {
                const int m = m0 + mt * 16 + (lane >> 4) * 4 + r;
                const int n = (w * 4 + nt) * 16 + (lane & 15);
                lp[(size_t)m * NEXP + n] = acc[mt][nt][r];
            }
        }
    }
}

// ---------------------------------------------------------------------------
// Kernel 2: sum K-split planes, per-token top-CAND candidates. One wave/token.
// Plane reads nontemporal (read-once) to keep W/whs cache-resident.
// ---------------------------------------------------------------------------
__global__ __launch_bounds__(256)
void topk_cand(const float* __restrict__ logits, int* __restrict__ cand,
               int nsplit) {
    const int lane  = threadIdx.x & 63;
    const int token = blockIdx.x * 4 + (threadIdx.x >> 6);
    const float* lp = logits + (size_t)token * NEXP;

    float s[4];
    #pragma unroll
    for (int j = 0; j < 4; ++j) s[j] = 0.f;
    for (int p = 0; p < nsplit; ++p) {
        const float* pp = lp + (size_t)p * TOKENS * NEXP;
        #pragma unroll
        for (int j = 0; j < 4; ++j)
            s[j] += __builtin_nontemporal_load(pp + j * 64 + lane);
    }

    int mye = 0;
    #pragma unroll
    for (int r = 0; r < CAND; ++r) {
        float bv = s[0];
        int   be = lane;
        #pragma unroll
        for (int j = 1; j < 4; ++j) {
            if (s[j] > bv) { bv = s[j]; be = j * 64 + lane; }
        }
        #pragma unroll
        for (int off = 32; off > 0; off >>= 1) {
            const float ov = __shfl_xor(bv, off, 64);
            const int   oe = __shfl_xor(be, off, 64);
            if (ov > bv || (ov == bv && oe < be)) { bv = ov; be = oe; }
        }
        if (lane == r) mye = be;
        if ((be & 63) == lane) s[be >> 6] = -1e30f;
    }

    if (lane < CAND) cand[token * CAND + lane] = mye;
}

// ---------------------------------------------------------------------------
// Kernel 3a: fp64 rescore partials, round 9 — K-split across XCDs.
// Round-3 post-mortem: W service pinned at 13-14 TB/s (=L3 rate) across
// occ=30%/68% and NT/no-NT -> 4 MiB W cannot be made resident in a 4 MiB
// per-XCD L2 (zero slack, set self-thrash). Fix: shrink the per-XCD W
// working set. Grid (KSL=8, TOKENS): linear wgid = s + 8*t, round-robin
// wg->XCD puts all slice-s blocks on XCD s -> each L2 only sees
// W[:, s*512..] = 0.5 MiB (3.5 MiB slack) -> 1.5 GB of W reads become L2
// hits (~34.5 TB/s agg) instead of L3 (~13). If the mapping assumption
// fails, degrades to current behavior (neutral).
// Block: 4 waves x 3 cands, x slice (2 KB) LDS-staged NT, W loads normal.
// Partials (fp64) to ws, combined by rescore_fin.
// ---------------------------------------------------------------------------
__global__ __launch_bounds__(256)
void rescore_part(const float* __restrict__ x, const float* __restrict__ w,
                  const int* __restrict__ cand, double* __restrict__ part) {
    __shared__ float xs[KSW];           // 2 KB: this token's x slice

    const int s     = blockIdx.x;       // k-slice 0..7 (-> XCD s)
    const int token = blockIdx.y;
    const int wave  = threadIdx.x >> 6, lane = threadIdx.x & 63;

    // Stage x slice -> LDS (waves 0,1: 64 lanes x 16 B = 1 KB each), NT.
    if (wave < 2) {
        const float* gp = x + (size_t)token * DIM + s * KSW + wave * 256 + lane * 4;
        __builtin_amdgcn_global_load_lds((gas_ptr)gp, (las_ptr)&xs[wave * 256],
                                         16, 0, 2 /* NT */);
    }

    // This wave's 3 candidates (scalarized bases into this k-slice).
    int ce[3];
    const f32x4* wp[3];
    #pragma unroll
    for (int j = 0; j < 3; ++j) {
        ce[j] = __builtin_amdgcn_readfirstlane(cand[token * CAND + wave * 3 + j]);
        wp[j] = (const f32x4*)(w + (size_t)ce[j] * DIM + s * KSW);
    }

    // W loads issue before the barrier (independent of xs).
    f32x4 wv0[3], wv1[3];
    #pragma unroll
    for (int j = 0; j < 3; ++j) {
        wv0[j] = wp[j][lane];
        wv1[j] = wp[j][64 + lane];
    }

    __syncthreads();    // xs ready (barrier drains vmcnt)

    const f32x4 x0 = *(const f32x4*)&xs[lane * 4];
    const f32x4 x1 = *(const f32x4*)&xs[256 + lane * 4];
    const double a0 = (double)x0.x, a1 = (double)x0.y;
    const double a2 = (double)x0.z, a3 = (double)x0.w;
    const double b0 = (double)x1.x, b1 = (double)x1.y;
    const double b2 = (double)x1.z, b3 = (double)x1.w;

    double acc[3];
    #pragma unroll
    for (int j = 0; j < 3; ++j) {
        const f32x4 u = wv0[j], v = wv1[j];
        double t0;
        t0 = fma(a3, (double)u.w,
             fma(a2, (double)u.z,
             fma(a1, (double)u.y,
             fma(a0, (double)u.x, 0.0))));
        acc[j] = fma(b3, (double)v.w,
                 fma(b2, (double)v.z,
                 fma(b1, (double)v.y,
                 fma(b0, (double)v.x, t0))));
    }

    // Lane reduce within wave.
    #pragma unroll
    for (int off = 32; off > 0; off >>= 1) {
        #pragma unroll
        for (int j = 0; j < 3; ++j)
            acc[j] += __shfl_xor(acc[j], off, 64);
    }

    if (lane == 0) {
        #pragma unroll
        for (int j = 0; j < 3; ++j)
            part[((size_t)token * CAND + wave * 3 + j) * KSL + s] = acc[j];
    }
}

// ---------------------------------------------------------------------------
// Kernel 3b: combine slice partials, rank, sigmoid, normalize, write.
// One wave per token (4 tokens/block). Lane c<12 owns candidate c; all
// (tot, expert) pairs broadcast via shfl; every lane computes the full
// 12x12 ranking (same logic/tie-break as previous passing rounds).
// ---------------------------------------------------------------------------
__global__ __launch_bounds__(256)
void rescore_fin(const double* __restrict__ part, const int* __restrict__ cand,
                 float* __restrict__ out) {
    const int wave = threadIdx.x >> 6, lane = threadIdx.x & 63;
    const int token = blockIdx.x * 4 + wave;

    double tot = -1e300;
    int    ee  = 0x7fffffff;
    if (lane < CAND) {
        const double* pp = part + ((size_t)token * CAND + lane) * KSL;
        double t = 0.0;
        #pragma unroll
        for (int s = 0; s < KSL; ++s) t += pp[s];
        tot = t;
        ee  = cand[token * CAND + lane];
    }

    double tt[CAND];
    int    ei[CAND];
    #pragma unroll
    for (int j = 0; j < CAND; ++j) {
        tt[j] = __shfl(tot, j, 64);
        ei[j] = __shfl(ee,  j, 64);
    }

    int rank[CAND];
    #pragma unroll
    for (int c = 0; c < CAND; ++c) {
        int r = 0;
        #pragma unroll
        for (int j = 0; j < CAND; ++j) {
            if (j == c) continue;
            if (tt[j] > tt[c] || (tt[j] == tt[c] && ei[j] < ei[c])) ++r;
        }
        rank[c] = r;
    }

    float sig[CAND];
    float sum = 0.f;
    #pragma unroll
    for (int c = 0; c < CAND; ++c) {
        sig[c] = 1.0f / (1.0f + expf(-(float)tt[c]));
        if (rank[c] < TOPK) sum += sig[c];
    }

    if (lane < TOPK) {
        float g = 0.f; int eo = 0;
        #pragma unroll
        for (int c = 0; c < CAND; ++c)
            if (rank[c] == lane) { g = sig[c]; eo = ei[c]; }
        out[(size_t)token * TOPK + lane] = g / sum;
        out[(size_t)TOKENS * TOPK + (size_t)token * TOPK + lane] = (float)eo;
    }
}

extern "C" void kernel_launch(void* const* d_in, const int* in_sizes, int n_in,
                              void* d_out, int out_size, void* d_ws, size_t ws_size,
                              hipStream_t stream) {
    const float* x = (const float*)d_in[0];   // [8192, 4096]
    const float* w = (const float*)d_in[1];   // [256, 4096]
    float* out     = (float*)d_out;

    const size_t plane = (size_t)TOKENS * NEXP * sizeof(float);   // 8 MB
    const size_t fixed = (size_t)TOKENS * CAND * sizeof(int)
                       + (size_t)NEXP * DIM * sizeof(_Float16);
    int S = 4;
    if (ws_size < 4 * plane + fixed) S = (ws_size >= 2 * plane + fixed) ? 2 : 1;

    float*     logits = (float*)d_ws;
    int*       candp  = (int*)((char*)d_ws + (size_t)S * plane);
    _Float16*  whs    = (_Float16*)((char*)candp + (size_t)TOKENS * CAND * sizeof(int));
    // fp64 partials (6 MB) alias the logits planes: logits are dead after
    // topk_cand, and S*plane >= 8 MB > 6 MB in all fallback configs.
    double*    part   = (double*)d_ws;

    convert_w<<<512, 256, 0, stream>>>(w, whs);
    dim3 ggrid(TOKENS / MT4, S);
    gemm_v4<<<ggrid, 256, 0, stream>>>(x, whs, logits, DIM / S);
    topk_cand<<<TOKENS / 4, 256, 0, stream>>>(logits, candp, S);
    dim3 rgrid(KSL, TOKENS);
    rescore_part<<<rgrid, 256, 0, stream>>>(x, w, candp, part);
    rescore_fin<<<TOKENS / 4, 256, 0, stream>>>(part, candp, out);
}

// Round 5
// 315.262 us; speedup vs baseline: 1.1771x; 1.1771x over previous
//
#include <hip/hip_runtime.h>
#include <hip/hip_bf16.h>
#include <hip/hip_fp16.h>
#include <math.h>

// Problem constants
#define TOKENS   8192
#define DIM      4096
#define NEXP     256
#define TOPK     8
#define CAND     12

// GEMM tiling
#define MT4      64                // tokens per block
#define BK3      64                // k per staged chunk
#define KG       (DIM / 32)        // 128 k-fragment-groups in W

typedef _Float16 f16x8 __attribute__((ext_vector_type(8)));
typedef float    f32x4 __attribute__((ext_vector_type(4)));

typedef const __attribute__((address_space(1))) unsigned int* gas_ptr;
typedef       __attribute__((address_space(3))) unsigned int* las_ptr;

// ---------------------------------------------------------------------------
// Kernel 0: W fp32 -> fp16 in MFMA-B-fragment-swizzled order.
// 1 KB tiles, tile = ng*KG + kg covers experts [ng*16,+16) x k [kg*32,+32);
// chunk c = q*16+r holds B[n=ng*16+r][k=kg*32+q*8..+8] = lane c's B-fragment.
// ---------------------------------------------------------------------------
__global__ __launch_bounds__(256)
void convert_w(const float* __restrict__ w, _Float16* __restrict__ whs) {
    const int g = blockIdx.x * 256 + threadIdx.x;   // chunk id, 131072 total
    const int tile = g >> 6, c = g & 63;
    const int q = c >> 4, r = c & 15;
    const int ng = tile / KG, kg = tile % KG;
    const int n = ng * 16 + r, k = kg * 32 + q * 8;
    const float4 a = *(const float4*)(w + (size_t)n * DIM + k);
    const float4 b = *(const float4*)(w + (size_t)n * DIM + k + 4);
    f16x8 h;
    h[0] = (_Float16)a.x; h[1] = (_Float16)a.y;
    h[2] = (_Float16)a.z; h[3] = (_Float16)a.w;
    h[4] = (_Float16)b.x; h[5] = (_Float16)b.y;
    h[6] = (_Float16)b.z; h[7] = (_Float16)b.w;
    *(f16x8*)(whs + (size_t)g * 8) = h;
}

// ---------------------------------------------------------------------------
// Kernel 1: partial logits via fp16 MFMA, K-split over blockIdx.y.
// Block: 64 tokens x 256 experts, 256 thr = 4 waves, wave-tile 64x64
// (16 MFMA / 8KB LDS-read). LDS 40 KB -> 3 blocks/CU; grid 128*S blocks.
// B staged via global_load_lds(16B) from pre-swizzled whs; A cvt'd on the fly.
// Round-5: NT hints on x loads REVERTED (round-1 NT cost ~+20us on the
// non-rescore kernels; W never became L2-resident anyway, so the hint
// bought nothing).
// ---------------------------------------------------------------------------
__global__ __launch_bounds__(256, 3)
void gemm_v4(const float* __restrict__ x, const _Float16* __restrict__ whs,
             float* __restrict__ logits, int kspan) {
    __shared__ _Float16 As[8 * 512];    //  8 tiles x 1 KB = 8 KB
    __shared__ _Float16 Bs[32 * 512];   // 32 tiles x 1 KB = 32 KB

    const int t = threadIdx.x, w = t >> 6, lane = t & 63;
    const int m0 = blockIdx.x * MT4;
    const int kb = blockIdx.y * kspan;
    float* lp    = logits + (size_t)blockIdx.y * TOKENS * NEXP;

    // A staging: thread t -> row am (0..63), k-chunks ack, ack+1 (8 halves ea)
    const int am  = t >> 2;
    const int ack = (t & 3) * 2;
    const int amg = am >> 4, amr = am & 15;
    const int aoff0 = ((amg * 2 + (ack >> 2)) * 64 + (ack & 3) * 16 + amr) * 8;
    const int ack1  = ack + 1;
    const int aoff1 = ((amg * 2 + (ack1 >> 2)) * 64 + (ack1 & 3) * 16 + amr) * 8;

    f32x4 acc[4][4];
    #pragma unroll
    for (int i = 0; i < 4; ++i)
        #pragma unroll
        for (int j = 0; j < 4; ++j) acc[i][j] = (f32x4){0.f, 0.f, 0.f, 0.f};

    const float* xrow = x + (size_t)(m0 + am) * DIM + ack * 8;
    float4 xr0 = *(const float4*)(xrow + kb);
    float4 xr1 = *(const float4*)(xrow + kb + 4);
    float4 xr2 = *(const float4*)(xrow + kb + 8);
    float4 xr3 = *(const float4*)(xrow + kb + 12);

    for (int k0 = kb; k0 < kb + kspan; k0 += BK3) {
        // B DMA: wave w stages tiles ti = w*8 .. w*8+7
        #pragma unroll
        for (int c = 0; c < 8; ++c) {
            const int ti  = w * 8 + c;
            const int ng  = ti >> 1, kgl = ti & 1;
            const _Float16* gp = whs + ((size_t)(ng * KG + (k0 >> 5) + kgl)) * 512
                                     + lane * 8;
            __builtin_amdgcn_global_load_lds((gas_ptr)gp, (las_ptr)&Bs[ti * 512],
                                             16, 0, 0);
        }
        // A cvt + frag-order ds_write
        {
            f16x8 h0, h1;
            h0[0] = (_Float16)xr0.x; h0[1] = (_Float16)xr0.y;
            h0[2] = (_Float16)xr0.z; h0[3] = (_Float16)xr0.w;
            h0[4] = (_Float16)xr1.x; h0[5] = (_Float16)xr1.y;
            h0[6] = (_Float16)xr1.z; h0[7] = (_Float16)xr1.w;
            h1[0] = (_Float16)xr2.x; h1[1] = (_Float16)xr2.y;
            h1[2] = (_Float16)xr2.z; h1[3] = (_Float16)xr2.w;
            h1[4] = (_Float16)xr3.x; h1[5] = (_Float16)xr3.y;
            h1[6] = (_Float16)xr3.z; h1[7] = (_Float16)xr3.w;
            *(f16x8*)&As[aoff0] = h0;
            *(f16x8*)&As[aoff1] = h1;
        }
        __syncthreads();

        if (k0 + BK3 < kb + kspan) {
            xr0 = *(const float4*)(xrow + k0 + BK3);
            xr1 = *(const float4*)(xrow + k0 + BK3 + 4);
            xr2 = *(const float4*)(xrow + k0 + BK3 + 8);
            xr3 = *(const float4*)(xrow + k0 + BK3 + 12);
        }

        #pragma unroll
        for (int kk = 0; kk < 2; ++kk) {
            f16x8 af[4], bf[4];
            #pragma unroll
            for (int mt = 0; mt < 4; ++mt)
                af[mt] = *(const f16x8*)&As[((mt * 2 + kk) * 64 + lane) * 8];
            #pragma unroll
            for (int nt = 0; nt < 4; ++nt)
                bf[nt] = *(const f16x8*)&Bs[(((w * 4 + nt) * 2 + kk) * 64 + lane) * 8];
            #pragma unroll
            for (int mt = 0; mt < 4; ++mt)
                #pragma unroll
                for (int nt = 0; nt < 4; ++nt)
                    acc[mt][nt] = __builtin_amdgcn_mfma_f32_16x16x32_f16(
                        af[mt], bf[nt], acc[mt][nt], 0, 0, 0);
        }
        __syncthreads();
    }

    // epilogue: C/D layout col=lane&15, row=(lane>>4)*4+reg
    #pragma unroll
    for (int mt = 0; mt < 4; ++mt) {
        #pragma unroll
        for (int nt = 0; nt < 4; ++nt) {
            #pragma unroll
            for (int r = 0; r < 4; ++r) {
                const int m = m0 + mt * 16 + (lane >> 4) * 4 + r;
                const int n = (w * 4 + nt) * 16 + (lane & 15);
                lp[(size_t)m * NEXP + n] = acc[mt][nt][r];
            }
        }
    }
}

// ---------------------------------------------------------------------------
// Kernel 2: sum K-split planes, per-token top-CAND candidates. One wave/token.
// Round-5: NT hints reverted (see gemm_v4 note).
// ---------------------------------------------------------------------------
__global__ __launch_bounds__(256)
void topk_cand(const float* __restrict__ logits, int* __restrict__ cand,
               int nsplit) {
    const int lane  = threadIdx.x & 63;
    const int token = blockIdx.x * 4 + (threadIdx.x >> 6);
    const float* lp = logits + (size_t)token * NEXP;

    float s[4];
    #pragma unroll
    for (int j = 0; j < 4; ++j) s[j] = 0.f;
    for (int p = 0; p < nsplit; ++p) {
        const float* pp = lp + (size_t)p * TOKENS * NEXP;
        #pragma unroll
        for (int j = 0; j < 4; ++j) s[j] += pp[j * 64 + lane];
    }

    int mye = 0;
    #pragma unroll
    for (int r = 0; r < CAND; ++r) {
        float bv = s[0];
        int   be = lane;
        #pragma unroll
        for (int j = 1; j < 4; ++j) {
            if (s[j] > bv) { bv = s[j]; be = j * 64 + lane; }
        }
        #pragma unroll
        for (int off = 32; off > 0; off >>= 1) {
            const float ov = __shfl_xor(bv, off, 64);
            const int   oe = __shfl_xor(be, off, 64);
            if (ov > bv || (ov == bv && oe < be)) { bv = ov; be = oe; }
        }
        if (lane == r) mye = be;
        if ((be & 63) == lane) s[be >> 6] = -1e30f;
    }

    if (lane < CAND) cand[token * CAND + lane] = mye;
}

// ---------------------------------------------------------------------------
// Kernel 3: fp64 rescore, round 10 — round-3 structure + triple-buffered W.
// History: W+x cache traffic (1.63 GB) served at 14-15.4 TB/s in EVERY
// config (occ 30%/68%, NT, XCD-pinned K-split) -> consistent with an
// aggregate L3 BW ceiling. Round-4's K-split reverted (overhead, no BW
// gain). This round's last latency test: W loads issued 2 iters ahead
// (wb[3][3], statically indexed under full unroll). If dur stays ~106,
// the shared-BW floor is confirmed and rescore is done.
// Structure: 1 block = 1 token, 4 waves, 3 candidates/wave, x row staged
// once to LDS (NT), cross-wave combine in LDS, wave 0 ranks+writes.
// ---------------------------------------------------------------------------
__global__ __launch_bounds__(256)
void rescore(const float* __restrict__ x, const float* __restrict__ w,
             const int* __restrict__ cand, float* __restrict__ out) {
    __shared__ float  xs[DIM];          // 16 KB: this token's x row
    __shared__ double stot[CAND];
    __shared__ int    sce[CAND];

    const int t = threadIdx.x, wave = t >> 6, lane = t & 63;
    const int token = blockIdx.x;

    // Stage x row -> LDS, NT (read-once stream).
    // global_load_lds dest is wave-uniform base + lane*16.
    const float* xrow = x + (size_t)token * DIM;
    #pragma unroll
    for (int r = 0; r < 4; ++r) {
        const float* gp = xrow + r * 1024 + wave * 256 + lane * 4;
        __builtin_amdgcn_global_load_lds((gas_ptr)gp,
                                         (las_ptr)&xs[r * 1024 + wave * 256],
                                         16, 0, 2 /* NT */);
    }

    // This wave's 3 candidates (scalarized bases).
    int ce[3];
    const f32x4* wp[3];
    #pragma unroll
    for (int j = 0; j < 3; ++j) {
        ce[j] = __builtin_amdgcn_readfirstlane(cand[token * CAND + wave * 3 + j]);
        wp[j] = (const f32x4*)(w + (size_t)ce[j] * DIM);
    }

    double acc[3];
    #pragma unroll
    for (int j = 0; j < 3; ++j) acc[j] = 0.0;

    // Triple buffer: loads for iter i issue at iter i-2.
    f32x4 wb[3][3];
    #pragma unroll
    for (int j = 0; j < 3; ++j) wb[0][j] = wp[j][lane];
    #pragma unroll
    for (int j = 0; j < 3; ++j) wb[1][j] = wp[j][64 + lane];

    __syncthreads();   // xs ready (syncthreads drains vmcnt before barrier)

    #pragma unroll
    for (int i = 0; i < 16; ++i) {
        const int cur = i % 3, nxt = (i + 2) % 3;   // constants under unroll
        if (i < 14) {
            const int o = lane + (i + 2) * 64;
            #pragma unroll
            for (int j = 0; j < 3; ++j) wb[nxt][j] = wp[j][o];
        }
        const f32x4 xv = *(const f32x4*)&xs[(lane + i * 64) * 4];
        const double dx = (double)xv.x, dy = (double)xv.y;
        const double dz = (double)xv.z, dw = (double)xv.w;
        #pragma unroll
        for (int j = 0; j < 3; ++j) {
            const f32x4 wv = wb[cur][j];
            acc[j] = fma(dw, (double)wv.w,
                     fma(dz, (double)wv.z,
                     fma(dy, (double)wv.y,
                     fma(dx, (double)wv.x, acc[j]))));
        }
    }

    // Lane reduce within wave.
    #pragma unroll
    for (int off = 32; off > 0; off >>= 1) {
        #pragma unroll
        for (int j = 0; j < 3; ++j)
            acc[j] += __shfl_xor(acc[j], off, 64);
    }

    if (lane == 0) {
        #pragma unroll
        for (int j = 0; j < 3; ++j) {
            stot[wave * 3 + j] = acc[j];
            sce[wave * 3 + j]  = ce[j];
        }
    }
    __syncthreads();

    // Wave 0: rank the 12 candidates, sigmoid, normalize, write.
    if (wave == 0) {
        double tt[CAND];
        int    ee[CAND];
        #pragma unroll
        for (int c = 0; c < CAND; ++c) { tt[c] = stot[c]; ee[c] = sce[c]; }

        int rank[CAND];
        #pragma unroll
        for (int c = 0; c < CAND; ++c) {
            int r = 0;
            #pragma unroll
            for (int j = 0; j < CAND; ++j) {
                if (j == c) continue;
                if (tt[j] > tt[c] || (tt[j] == tt[c] && ee[j] < ee[c])) ++r;
            }
            rank[c] = r;
        }

        float sig[CAND];
        float sum = 0.f;
        #pragma unroll
        for (int c = 0; c < CAND; ++c) {
            sig[c] = 1.0f / (1.0f + expf(-(float)tt[c]));
            if (rank[c] < TOPK) sum += sig[c];
        }

        if (lane < TOPK) {
            float g = 0.f; int ei = 0;
            #pragma unroll
            for (int c = 0; c < CAND; ++c)
                if (rank[c] == lane) { g = sig[c]; ei = ee[c]; }
            out[(size_t)token * TOPK + lane] = g / sum;
            out[(size_t)TOKENS * TOPK + (size_t)token * TOPK + lane] = (float)ei;
        }
    }
}

extern "C" void kernel_launch(void* const* d_in, const int* in_sizes, int n_in,
                              void* d_out, int out_size, void* d_ws, size_t ws_size,
                              hipStream_t stream) {
    const float* x = (const float*)d_in[0];   // [8192, 4096]
    const float* w = (const float*)d_in[1];   // [256, 4096]
    float* out     = (float*)d_out;

    const size_t plane = (size_t)TOKENS * NEXP * sizeof(float);   // 8 MB
    const size_t fixed = (size_t)TOKENS * CAND * sizeof(int)
                       + (size_t)NEXP * DIM * sizeof(_Float16);
    int S = 4;
    if (ws_size < 4 * plane + fixed) S = (ws_size >= 2 * plane + fixed) ? 2 : 1;

    float*     logits = (float*)d_ws;
    int*       candp  = (int*)((char*)d_ws + (size_t)S * plane);
    _Float16*  whs    = (_Float16*)((char*)candp + (size_t)TOKENS * CAND * sizeof(int));

    convert_w<<<512, 256, 0, stream>>>(w, whs);
    dim3 ggrid(TOKENS / MT4, S);
    gemm_v4<<<ggrid, 256, 0, stream>>>(x, whs, logits, DIM / S);
    topk_cand<<<TOKENS / 4, 256, 0, stream>>>(logits, candp, S);
    rescore<<<TOKENS, 256, 0, stream>>>(x, w, candp, out);
}